// Round 10
// baseline (384.149 us; speedup 1.0000x reference)
//
#include <hip/hip_runtime.h>

#define T_SEQ 8192
#define NH 16
#define HD 64
#define DIM 1024
#define ROWS 16384   // 2*8192
#define CHK 256
#define NCHK 32

typedef float f32x4 __attribute__((ext_vector_type(4)));
typedef __bf16 bf16x8 __attribute__((ext_vector_type(8)));
typedef short short8 __attribute__((ext_vector_type(8)));
typedef short short4v __attribute__((ext_vector_type(4)));
typedef unsigned short ushort_t;

__device__ __forceinline__ float bf2f(ushort_t u){ return __uint_as_float(((unsigned)u)<<16); }
__device__ __forceinline__ ushort_t f2bf(float f){
  unsigned u = __float_as_uint(f);
  u += 0x7FFFu + ((u>>16)&1u);
  return (ushort_t)(u>>16);
}
#define BFLO(u) __uint_as_float((u)<<16)
#define BFHI(u) __uint_as_float((u)&0xFFFF0000u)
#define MFMA16(a,b,c) __builtin_amdgcn_mfma_f32_16x16x32_bf16((a),(b),(c),0,0,0)

// ---------------- transpose 5 weights 1024x1024 fp32 -> bf16 (N-major) ----------------
__global__ __launch_bounds__(256) void transpose_all(const float* __restrict__ Wq,
    const float* __restrict__ Wk, const float* __restrict__ Wv,
    const float* __restrict__ Wg, const float* __restrict__ Wo,
    ushort_t* __restrict__ wcat, ushort_t* __restrict__ wot){
  int z = blockIdx.z;
  const float* W = (z==0)?Wq:(z==1)?Wk:(z==2)?Wv:(z==3)?Wg:Wo;
  ushort_t* D = (z<4)? (wcat + (size_t)z*DIM*DIM) : wot;
  __shared__ float tile[64][65];
  int k0 = blockIdx.x*64, n0 = blockIdx.y*64;
  int tid = threadIdx.x;
  #pragma unroll
  for (int it=0; it<16; ++it){
    int idx = tid + it*256;
    int r = idx>>6, c = idx&63;
    tile[r][c] = W[(size_t)(k0+r)*DIM + n0+c];
  }
  __syncthreads();
  #pragma unroll
  for (int it=0; it<16; ++it){
    int idx = tid + it*256;
    int r = idx>>6, c = idx&63;
    D[(size_t)(n0+r)*DIM + k0+c] = f2bf(tile[c][r]);
  }
}

// ---------------- MFMA GEMM (R2-proven, 910 TF): C[M,N] = A[M,K] * Bt[N,K]^T ----------------
// yoff: ssq slot offset (gemm1 is split into two N=2048 launches for profiling clarity).
template<int OUT_BF16>
__global__ __launch_bounds__(256,2) void gemm_bt(const ushort_t* __restrict__ A,
    const ushort_t* __restrict__ Bt, void* __restrict__ Cv, int M, int N, int K,
    float* __restrict__ ssqp, int yoff){
  __shared__ __align__(16) ushort_t As[128*64];
  __shared__ __align__(16) ushort_t Bs[128*64];
  int tid = threadIdx.x;
  int lane = tid & 63, wid = tid >> 6;
  int wr = wid >> 1, wc = wid & 1;
  int m0 = blockIdx.x * 128, n0 = blockIdx.y * 128;
  f32x4 acc[4][4] = {};
  int srow = tid >> 3;
  int sg = tid & 7;
  const int nkt = K >> 6;
  for (int kt = 0; kt < nkt; ++kt){
    short8 ra[4], rb[4];
    #pragma unroll
    for (int s = 0; s < 4; ++s){
      int row = s*32 + srow;
      int gl = sg ^ (row & 7);
      ra[s] = *(const short8*)&A[(size_t)(m0 + row)*K + kt*64 + gl*8];
      rb[s] = *(const short8*)&Bt[(size_t)(n0 + row)*K + kt*64 + gl*8];
    }
    __syncthreads();
    #pragma unroll
    for (int s = 0; s < 4; ++s){
      int row = s*32 + srow;
      *(short8*)&As[row*64 + sg*8] = ra[s];
      *(short8*)&Bs[row*64 + sg*8] = rb[s];
    }
    __syncthreads();
    #pragma unroll
    for (int kk = 0; kk < 2; ++kk){
      bf16x8 af[4], bfv[4];
      #pragma unroll
      for (int m = 0; m < 4; ++m){
        int row = wr*64 + m*16 + (lane & 15);
        int g = kk*4 + (lane >> 4);
        af[m] = *(const bf16x8*)&As[row*64 + ((g ^ (row & 7))<<3)];
      }
      #pragma unroll
      for (int n = 0; n < 4; ++n){
        int row = wc*64 + n*16 + (lane & 15);
        int g = kk*4 + (lane >> 4);
        bfv[n] = *(const bf16x8*)&Bs[row*64 + ((g ^ (row & 7))<<3)];
      }
      #pragma unroll
      for (int m = 0; m < 4; ++m)
        #pragma unroll
        for (int n = 0; n < 4; ++n)
          acc[m][n] = MFMA16(af[m], bfv[n], acc[m][n]);
    }
  }
  #pragma unroll
  for (int m = 0; m < 4; ++m){
    int row = m0 + wr*64 + m*16 + (lane>>4)*4;
    #pragma unroll
    for (int n = 0; n < 4; ++n){
      int col = n0 + wc*64 + n*16 + (lane & 15);
      #pragma unroll
      for (int r = 0; r < 4; ++r){
        float v = acc[m][n][r];
        if (OUT_BF16) ((ushort_t*)Cv)[(size_t)(row+r)*N + col] = f2bf(v);
        else          ((float*)Cv)[(size_t)(row+r)*N + col] = v;
      }
    }
  }
  if (OUT_BF16 && (yoff + (int)blockIdx.y) < 24){
    int slot = (yoff + blockIdx.y)*2 + wc;
    #pragma unroll
    for (int m = 0; m < 4; ++m){
      #pragma unroll
      for (int r = 0; r < 4; ++r){
        float s = 0.f;
        #pragma unroll
        for (int n = 0; n < 4; ++n){ float xx = acc[m][n][r]; s += xx*xx; }
        s += __shfl_xor(s,1); s += __shfl_xor(s,2);
        s += __shfl_xor(s,4); s += __shfl_xor(s,8);
        if ((lane & 15) == 0){
          int row = m0 + wr*64 + m*16 + (lane>>4)*4 + r;
          ssqp[(size_t)slot*ROWS + row] = s;
        }
      }
    }
  }
}

// ---------------- combine ssq partials -> inverse rms per (mat,row) ----------------
__global__ __launch_bounds__(256) void rms_combine(const float* __restrict__ ssqp,
                                                   float* __restrict__ rmsb){
  int idx = blockIdx.x*256 + threadIdx.x;    // 3*16384
  int mat = idx >> 14, row = idx & (ROWS-1);
  float s = 0.f;
  #pragma unroll
  for (int k=0;k<16;++k) s += ssqp[(size_t)(mat*16+k)*ROWS + row];
  rmsb[idx] = rsqrtf(s*(1.f/1024.f)+1e-6f);
}

// ---------------- gt = logsigmoid(x @ Wgt)/16  +  fused x->bf16 cast ----------------
__global__ __launch_bounds__(256) void gt_ker(const float* __restrict__ x,
    const float* __restrict__ Wgt, float* __restrict__ gtb, ushort_t* __restrict__ xbf){
  int row = blockIdx.x; int b = row>>13; int t = row & (T_SEQ-1);
  int tid = threadIdx.x; int lane = tid&63; int w = tid>>6;
  __shared__ float xs[1024];
  #pragma unroll
  for (int i=0;i<4;++i) xs[tid+256*i] = x[(size_t)row*DIM + tid+256*i];
  __syncthreads();
  short4v xb4;
  #pragma unroll
  for (int k2=0;k2<4;++k2) xb4[k2] = (short)f2bf(xs[tid*4+k2]);
  *(short4v*)&xbf[(size_t)row*DIM + tid*4] = xb4;
  float a0=0,a1=0,a2=0,a3=0;
  #pragma unroll
  for (int jj=0;jj<16;++jj){
    int j = lane + 64*jj;
    float xv = xs[j];
    const float* wp = &Wgt[(size_t)j*NH + w*4];
    a0 += xv*wp[0]; a1 += xv*wp[1]; a2 += xv*wp[2]; a3 += xv*wp[3];
  }
  #pragma unroll
  for (int off=32; off>=1; off>>=1){
    a0 += __shfl_xor(a0, off); a1 += __shfl_xor(a1, off);
    a2 += __shfl_xor(a2, off); a3 += __shfl_xor(a3, off);
  }
  if (lane==0){
    float za[4] = {a0,a1,a2,a3};
    #pragma unroll
    for (int i=0;i<4;++i){
      float z = za[i];
      float ls = fminf(z,0.f) - log1pf(__expf(-fabsf(z)));
      gtb[((size_t)(b*NH + w*4 + i))*T_SEQ + t] = ls * (1.f/16.f);
    }
  }
}

// ---------------- attention phase 1 (MFMA): kv = (k*rms_k*dec)^T (v*rms_v), kv bf16 [e][d] ----------------
__global__ __launch_bounds__(512,2) void attn_p1(const ushort_t* __restrict__ qkvg,
    const float* __restrict__ gtb, const float* __restrict__ rmsb,
    float* __restrict__ Bb, ushort_t* __restrict__ kvb){
  __shared__ __align__(16) ushort_t sh2[32768];   // kdt [64][256] | vt [64][256], swizzled
  __shared__ float bcf[256];
  __shared__ float tmp4[4];
  ushort_t* kdt = sh2;
  ushort_t* vt  = sh2 + 16384;
  int bid = blockIdx.x; int n = bid&31; int bh = bid>>5; int b = bh>>4; int h = bh&15;
  int t0 = n*CHK; int tid = threadIdx.x; int lane = tid&63; int w = tid>>6;
  float vscan = 0.f;
  if (tid < 256){
    vscan = gtb[(size_t)bh*T_SEQ + t0 + tid];
    #pragma unroll
    for (int off=1; off<64; off<<=1){ float u = __shfl_up(vscan, off); if (lane>=off) vscan += u; }
    if (lane==63) tmp4[w] = vscan;
  }
  __syncthreads();
  float Bn = tmp4[0]+tmp4[1]+tmp4[2]+tmp4[3];
  if (tid < 256){
    float pre=0;
    #pragma unroll
    for (int i=0;i<4;++i) if (i<w) pre += tmp4[i];
    bcf[tid] = vscan + pre;
  }
  if (tid==0) Bb[bid] = Bn;
  __syncthreads();
  {
    int j = tid>>1, dh = tid&1;
    int grow = b*T_SEQ + t0 + j;
    size_t rowb = (size_t)grow*4096;
    float fk = rmsb[ROWS + grow] * __expf(Bn - bcf[j]);
    float fv = rmsb[2*ROWS + grow];
    #pragma unroll
    for (int q8=0; q8<4; ++q8){
      short8 k8 = *(const short8*)&qkvg[rowb + 1024 + h*HD + dh*32 + q8*8];
      short8 v8 = *(const short8*)&qkvg[rowb + 2048 + h*HD + dh*32 + q8*8];
      #pragma unroll
      for (int kk=0; kk<8; ++kk){
        int d = dh*32 + q8*8 + kk;
        kdt[(d<<8) + (((j>>3)^(d&7))<<3) + (j&7)] = f2bf(bf2f((ushort_t)k8[kk])*fk);
        vt [(d<<8) + (((j>>3)^(d&7))<<3) + (j&7)] = f2bf(bf2f((ushort_t)v8[kk])*fv);
      }
    }
  }
  __syncthreads();
  if (w < 4){
    f32x4 acc[4] = {};
    #pragma unroll
    for (int s=0; s<8; ++s){
      int d = w*16 + (lane&15);
      int jj = s*32 + (lane>>4)*8;
      bf16x8 ka = *(const bf16x8*)&kdt[(d<<8) + (((jj>>3)^(d&7))<<3)];
      #pragma unroll
      for (int et=0; et<4; ++et){
        int e = et*16 + (lane&15);
        bf16x8 vf = *(const bf16x8*)&vt[(e<<8) + (((jj>>3)^(e&7))<<3)];
        acc[et] = MFMA16(ka, vf, acc[et]);
      }
    }
    ushort_t* kvp = &kvb[(size_t)bid*4096];
    #pragma unroll
    for (int et=0; et<4; ++et)
      #pragma unroll
      for (int r=0; r<4; ++r)
        kvp[(et*16 + (lane&15))*64 + w*16 + (lane>>4)*4 + r] = f2bf(acc[et][r]);
  }
}

// ---------------- state scan: one thread per (bh, e*64+d), coalesced, bf16 kv ----------------
__global__ __launch_bounds__(256) void scan_ker(const ushort_t* __restrict__ kvb,
    const float* __restrict__ Bb, ushort_t* __restrict__ Sb){
  int gidx = blockIdx.x*256 + threadIdx.x;
  int bh = gidx >> 12; int f = gidx & 4095;
  float S = 0.f;
  const ushort_t* kp = &kvb[(size_t)bh*NCHK*4096 + f];
  ushort_t* sp = &Sb[(size_t)bh*NCHK*4096 + f];
  for (int n=0;n<NCHK;++n){
    sp[(size_t)n*4096] = f2bf(S);
    S = __expf(Bb[bh*NCHK+n])*S + bf2f(kp[(size_t)n*4096]);
  }
}

// ---------------- attention phase 3: swapped QK^T + in-register P (no LDS round-trip) ----------------
// s2 = MFMA(kf, qf) puts P[k][q] with q = lane&15 (lane-local row). Scale+mask, pack to
// bf16 pairs, shfl-exchange within the 4-lane q-column group -> PV A-fragment in regs.
// ps LDS retained only for the store-redistribution epilogue.
__global__ __launch_bounds__(512,2) void attn_p3(const ushort_t* __restrict__ qkvg,
    const float* __restrict__ gtb, const float* __restrict__ rmsb,
    const ushort_t* __restrict__ Sb, ushort_t* __restrict__ oact){
  __shared__ __align__(16) ushort_t sh[(32768+16384+1024+32+2048)/2];
  ushort_t* vt = sh;                         // [e=64][j=256] swizzled
  ushort_t* ps = sh + 16384;                 // per-wave [32][32] swizzled (epilogue only)
  float* bcs = (float*)(sh + 24576);
  float* tmp = (float*)(sh + 25088);
  float* rqs = (float*)(sh + 25104);
  float* rks = (float*)(sh + 25616);
  int bid = blockIdx.x; int n = bid&31; int bh = bid>>5; int b = bh>>4; int h = bh&15;
  int t0 = n*CHK; int tid = threadIdx.x; int lane = tid&63; int w = tid>>6;
  int wrow = w*32;
  size_t chunkbase = (size_t)b*T_SEQ + t0;
  int qcol = lane & 15, hi = lane >> 4;
  // hoisted q fragment loads
  bf16x8 qf[2][2];
  #pragma unroll
  for (int rt=0; rt<2; ++rt)
    #pragma unroll
    for (int s=0; s<2; ++s)
      qf[rt][s] = *(const bf16x8*)&qkvg[(chunkbase + wrow + rt*16 + qcol)*4096
                                        + h*HD + s*32 + hi*8];
  // cumsum
  float vscan = 0.f;
  if (tid < 256){
    vscan = gtb[(size_t)bh*T_SEQ + t0 + tid];
    #pragma unroll
    for (int off=1; off<64; off<<=1){ float u = __shfl_up(vscan, off); if (lane>=off) vscan += u; }
    if (lane==63) tmp[w] = vscan;
  }
  __syncthreads();
  if (tid < 256){
    float pre=0;
    #pragma unroll
    for (int i=0;i<4;++i) if (i<w) pre += tmp[i];
    bcs[tid] = vscan + pre;
    int grow = b*T_SEQ + t0 + tid;
    rqs[tid] = rmsb[grow];
    rks[tid] = rmsb[ROWS + grow];
  }
  // vt staging
  {
    int j = tid>>1, ehalf = tid&1;
    int grow = b*T_SEQ + t0 + j;
    size_t rowb = (size_t)grow*4096;
    float fv = rmsb[2*ROWS + grow];
    #pragma unroll
    for (int q8=0; q8<4; ++q8){
      short8 v8 = *(const short8*)&qkvg[rowb + 2048 + h*HD + ehalf*32 + q8*8];
      #pragma unroll
      for (int kk=0; kk<8; ++kk){
        int e = ehalf*32 + q8*8 + kk;
        vt[(e<<8) + (((j>>3)^(e&7))<<3) + (j&7)] = f2bf(bf2f((ushort_t)v8[kk])*fv);
      }
    }
  }
  __syncthreads();
  // cross: O = q @ S^T
  f32x4 o_[2][4] = {};
  #pragma unroll
  for (int s=0; s<2; ++s)
    #pragma unroll
    for (int et=0; et<4; ++et){
      bf16x8 stf = *(const bf16x8*)&Sb[(size_t)bid*4096 + (et*16 + qcol)*64 + s*32 + hi*8];
      #pragma unroll
      for (int rt=0; rt<2; ++rt)
        o_[rt][et] = MFMA16(qf[rt][s], stf, o_[rt][et]);
    }
  #pragma unroll
  for (int rt=0; rt<2; ++rt)
    #pragma unroll
    for (int rr=0; rr<4; ++rr){
      int ri = wrow + rt*16 + hi*4 + rr;
      float fs = 0.125f*__expf(bcs[ri])*rqs[ri];
      #pragma unroll
      for (int et=0; et<4; ++et) o_[rt][et][rr] *= fs;
    }
  // per-lane q constants for the swapped-P path
  float rqv[2], bqv[2];
  #pragma unroll
  for (int rt=0; rt<2; ++rt){
    int qr = wrow + rt*16 + qcol;
    rqv[rt] = rqs[qr]; bqv[rt] = bcs[qr];
  }
  int s0 = qcol + 32*(hi&1), s1 = s0 + 16;
  bool ctp = (hi >> 1) != 0;
  // intra loop
  for (int hb=0; hb<=w; ++hb){
    int jbase = hb*32;
    bool dia = (hb == w);
    // k fragments (streamed)
    bf16x8 kf[2][2];
    #pragma unroll
    for (int s=0; s<2; ++s)
      #pragma unroll
      for (int ct=0; ct<2; ++ct)
        kf[s][ct] = *(const bf16x8*)&qkvg[(chunkbase + jbase + ct*16 + qcol)*4096
                                          + 1024 + h*HD + s*32 + hi*8];
    // swapped QK^T: s2[rt][ct] rows = k, cols = q(lane-local)
    f32x4 s2[2][2] = {};
    #pragma unroll
    for (int s=0; s<2; ++s)
      #pragma unroll
      for (int ct=0; ct<2; ++ct)
        #pragma unroll
        for (int rt=0; rt<2; ++rt)
          s2[rt][ct] = MFMA16(kf[s][ct], qf[rt][s], s2[rt][ct]);
    // V fragments
    bf16x8 vf[4];
    #pragma unroll
    for (int et=0; et<4; ++et){
      int e = et*16 + qcol;
      int jj = jbase + hi*8;
      vf[et] = *(const bf16x8*)&vt[(e<<8) + (((jj>>3) ^ (e&7))<<3)];
    }
    // scale + pack + exchange + PV, per rt
    #pragma unroll
    for (int rt=0; rt<2; ++rt){
      int qr = wrow + rt*16 + qcol;
      unsigned wd[2][2];
      #pragma unroll
      for (int ct=0; ct<2; ++ct){
        float pv[4];
        #pragma unroll
        for (int rr=0; rr<4; ++rr){
          int kr = jbase + ct*16 + hi*4 + rr;
          float val = s2[rt][ct][rr] * 0.125f * rqv[rt] * rks[kr] * __expf(bqv[rt] - bcs[kr]);
          if (dia && kr > qr) val = 0.f;
          pv[rr] = val;
        }
        wd[ct][0] = ((unsigned)f2bf(pv[1])<<16) | f2bf(pv[0]);
        wd[ct][1] = ((unsigned)f2bf(pv[3])<<16) | f2bf(pv[2]);
      }
      unsigned a00 = (unsigned)__shfl((int)wd[0][0], s0);
      unsigned a10 = (unsigned)__shfl((int)wd[1][0], s0);
      unsigned a01 = (unsigned)__shfl((int)wd[0][1], s0);
      unsigned a11 = (unsigned)__shfl((int)wd[1][1], s0);
      unsigned b00 = (unsigned)__shfl((int)wd[0][0], s1);
      unsigned b10 = (unsigned)__shfl((int)wd[1][0], s1);
      unsigned b01 = (unsigned)__shfl((int)wd[0][1], s1);
      unsigned b11 = (unsigned)__shfl((int)wd[1][1], s1);
      union { unsigned u[4]; bf16x8 v; } pa;
      pa.u[0] = ctp ? a10 : a00;
      pa.u[1] = ctp ? a11 : a01;
      pa.u[2] = ctp ? b10 : b00;
      pa.u[3] = ctp ? b11 : b01;
      #pragma unroll
      for (int et=0; et<4; ++et)
        o_[rt][et] = MFMA16(pa.v, vf[et], o_[rt][et]);
    }
  }
  // epilogue: per-row rmsnorm (d=64), silu(g), coalesced store via ps
  float rms8[2][4];
  #pragma unroll
  for (int rt=0; rt<2; ++rt)
    #pragma unroll
    for (int rr=0; rr<4; ++rr){
      float ssq = 0.f;
      #pragma unroll
      for (int et=0; et<4; ++et){ float xx = o_[rt][et][rr]; ssq += xx*xx; }
      ssq += __shfl_xor(ssq,1); ssq += __shfl_xor(ssq,2);
      ssq += __shfl_xor(ssq,4); ssq += __shfl_xor(ssq,8);
      rms8[rt][rr] = rsqrtf(ssq*(1.f/64.f)+1e-6f);
    }
  #pragma unroll
  for (int eh=0; eh<2; ++eh){
    #pragma unroll
    for (int rt=0; rt<2; ++rt)
      #pragma unroll
      for (int e2=0; e2<2; ++e2){
        int et = eh*2 + e2;
        #pragma unroll
        for (int rr=0; rr<4; ++rr){
          int pi = rt*16 + hi*4 + rr;
          int pj = e2*16 + qcol;
          ps[w*1024 + pi*32 + (((pj>>3) ^ ((pi>>2)&3))<<3) + (pj&7)] =
            f2bf(o_[rt][et][rr]*rms8[rt][rr]);
        }
      }
    int i2 = lane&31, e16 = (lane>>5)*16;
    int gr0 = e16>>3;
    int f = (i2>>2)&3;
    short8 ov0 = *(const short8*)&ps[w*1024 + i2*32 + ((gr0^f)<<3)];
    short8 ov1 = *(const short8*)&ps[w*1024 + i2*32 + (((gr0+1)^f)<<3)];
    size_t rowg = chunkbase + wrow + i2;
    short8 gv0 = *(const short8*)&qkvg[rowg*4096 + 3072 + h*HD + eh*32 + e16];
    short8 gv1 = *(const short8*)&qkvg[rowg*4096 + 3072 + h*HD + eh*32 + e16 + 8];
    ushort_t outv[16];
    #pragma unroll
    for (int k=0;k<8;++k){
      float gf = bf2f((ushort_t)gv0[k]);
      float sg = gf/(1.f+__expf(-gf));
      outv[k] = f2bf(bf2f((ushort_t)ov0[k])*sg);
    }
    #pragma unroll
    for (int k=0;k<8;++k){
      float gf = bf2f((ushort_t)gv1[k]);
      float sg = gf/(1.f+__expf(-gf));
      outv[8+k] = f2bf(bf2f((ushort_t)ov1[k])*sg);
    }
    ushort_t* op = &oact[rowg*DIM + h*HD + eh*32 + e16];
    *(short8*)&op[0] = *(short8*)&outv[0];
    *(short8*)&op[8] = *(short8*)&outv[8];
  }
}

// ---------------- launch ----------------
extern "C" void kernel_launch(void* const* d_in, const int* in_sizes, int n_in,
                              void* d_out, int out_size, void* d_ws, size_t ws_size,
                              hipStream_t stream){
  const float* x  = (const float*)d_in[0];
  const float* Wq = (const float*)d_in[1];
  const float* Wk = (const float*)d_in[2];
  const float* Wv = (const float*)d_in[3];
  const float* Wg = (const float*)d_in[4];
  const float* Wgt= (const float*)d_in[5];
  const float* Wo = (const float*)d_in[6];
  float* out = (float*)d_out;

  char* p = (char*)d_ws;
  ushort_t* xbf  = (ushort_t*)p; p += (size_t)ROWS*DIM*2;
  ushort_t* wcat = (ushort_t*)p; p += (size_t)4*DIM*DIM*2;
  ushort_t* wot  = (ushort_t*)p; p += (size_t)DIM*DIM*2;
  ushort_t* qkvg = (ushort_t*)p; p += (size_t)ROWS*4096*2;
  float* gtb = (float*)p; p += (size_t)32*T_SEQ*4;
  float* Bb  = (float*)p; p += 1024*4;
  ushort_t* kvb = (ushort_t*)p; p += (size_t)1024*4096*2;
  ushort_t* Sb = (ushort_t*)p; p += (size_t)1024*4096*2;
  ushort_t* oact = (ushort_t*)p; p += (size_t)ROWS*DIM*2;
  float* ssqp = (float*)p; p += (size_t)48*ROWS*4;
  float* rmsb = (float*)p; p += (size_t)3*ROWS*4;
  if ((size_t)(p - (char*)d_ws) > ws_size) return;

  gt_ker<<<ROWS,256,0,stream>>>(x, Wgt, gtb, xbf);
  transpose_all<<<dim3(16,16,5),256,0,stream>>>(Wq, Wk, Wv, Wg, Wo, wcat, wot);
  // gemm1 split into two N=2048 launches (profiling clarity; C stride stays 4096)
  gemm_bt<1><<<dim3(ROWS/128, 16), 256, 0, stream>>>(xbf, wcat, qkvg, ROWS, 4096, DIM, ssqp, 0);
  gemm_bt<1><<<dim3(ROWS/128, 16), 256, 0, stream>>>(xbf, wcat + (size_t)2048*DIM,
                                                     qkvg + 2048, ROWS, 4096, DIM, ssqp, 16);
  rms_combine<<<(3*ROWS)/256,256,0,stream>>>(ssqp, rmsb);
  attn_p1<<<1024,512,0,stream>>>(qkvg, gtb, rmsb, Bb, kvb);
  scan_ker<<<512,256,0,stream>>>(kvb, Bb, Sb);
  attn_p3<<<1024,512,0,stream>>>(qkvg, gtb, rmsb, Sb, oact);
  gemm_bt<0><<<dim3(ROWS/128, 1024/128), 256, 0, stream>>>(oact, wot, out, ROWS, 1024, DIM, nullptr, 0);
}

// Round 11
// 320.558 us; speedup vs baseline: 1.1984x; 1.1984x over previous
//
#include <hip/hip_runtime.h>

#define T_SEQ 8192
#define NH 16
#define HD 64
#define DIM 1024
#define ROWS 16384   // 2*8192
#define CHK 256
#define NCHK 32

typedef float f32x4 __attribute__((ext_vector_type(4)));
typedef __bf16 bf16x8 __attribute__((ext_vector_type(8)));
typedef short short8 __attribute__((ext_vector_type(8)));
typedef short short4v __attribute__((ext_vector_type(4)));
typedef unsigned short ushort_t;

__device__ __forceinline__ float bf2f(ushort_t u){ return __uint_as_float(((unsigned)u)<<16); }
__device__ __forceinline__ ushort_t f2bf(float f){
  unsigned u = __float_as_uint(f);
  u += 0x7FFFu + ((u>>16)&1u);
  return (ushort_t)(u>>16);
}
#define BFLO(u) __uint_as_float((u)<<16)
#define BFHI(u) __uint_as_float((u)&0xFFFF0000u)
#define MFMA16(a,b,c) __builtin_amdgcn_mfma_f32_16x16x32_bf16((a),(b),(c),0,0,0)

// ---------------- transpose 5 weights 1024x1024 fp32 -> bf16 (N-major) ----------------
__global__ __launch_bounds__(256) void transpose_all(const float* __restrict__ Wq,
    const float* __restrict__ Wk, const float* __restrict__ Wv,
    const float* __restrict__ Wg, const float* __restrict__ Wo,
    ushort_t* __restrict__ wcat, ushort_t* __restrict__ wot){
  int z = blockIdx.z;
  const float* W = (z==0)?Wq:(z==1)?Wk:(z==2)?Wv:(z==3)?Wg:Wo;
  ushort_t* D = (z<4)? (wcat + (size_t)z*DIM*DIM) : wot;
  __shared__ float tile[64][65];
  int k0 = blockIdx.x*64, n0 = blockIdx.y*64;
  int tid = threadIdx.x;
  #pragma unroll
  for (int it=0; it<16; ++it){
    int idx = tid + it*256;
    int r = idx>>6, c = idx&63;
    tile[r][c] = W[(size_t)(k0+r)*DIM + n0+c];
  }
  __syncthreads();
  #pragma unroll
  for (int it=0; it<16; ++it){
    int idx = tid + it*256;
    int r = idx>>6, c = idx&63;
    D[(size_t)(n0+r)*DIM + k0+c] = f2bf(tile[c][r]);
  }
}

// ---------------- fused cast x->bf16 + gt = logsigmoid(x @ Wgt)/16 (MFMA) ----------------
// 256 blocks x 64 rows. Wgt^T staged once to LDS (bf16, padded rows). A-tile cast
// in-register (xbf write fused), swizzled LDS, 2 MFMA/K-step, x prefetched 1 step ahead.
__global__ __launch_bounds__(256,2) void cast_gt_ker(const float* __restrict__ x,
    const float* __restrict__ Wgt, ushort_t* __restrict__ xbf, float* __restrict__ gtb){
  __shared__ __align__(16) ushort_t As[64*64];        // 8 KB swizzled
  __shared__ __align__(16) ushort_t wgt_t[16*1040];   // 32.5 KB [n][k], row pad 16
  int tid = threadIdx.x, lane = tid&63, w = tid>>6;
  int r0 = blockIdx.x*64;
  #pragma unroll 4
  for (int i=0;i<64;++i){
    int idx = tid + i*256;                            // coalesced Wgt read
    wgt_t[(idx&15)*1040 + (idx>>4)] = f2bf(Wgt[idx]);
  }
  int arow = tid>>2;
  int acg = (tid&3)*2;
  const float* xrow = &x[(size_t)(r0+arow)*1024 + (tid&3)*16];
  ushort_t* xbrow = &xbf[(size_t)(r0+arow)*1024 + (tid&3)*16];
  int aslot0 = ((acg   ^ (arow&7))<<3);
  int aslot1 = (((acg+1) ^ (arow&7))<<3);
  f32x4 acc = {0.f,0.f,0.f,0.f};
  float4 f0 = *(const float4*)&xrow[0];
  float4 f1 = *(const float4*)&xrow[4];
  float4 f2 = *(const float4*)&xrow[8];
  float4 f3 = *(const float4*)&xrow[12];
  __syncthreads();                                    // wgt_t ready
  for (int kt=0; kt<16; ++kt){
    ushort_t c[16] = { f2bf(f0.x),f2bf(f0.y),f2bf(f0.z),f2bf(f0.w),
                       f2bf(f1.x),f2bf(f1.y),f2bf(f1.z),f2bf(f1.w),
                       f2bf(f2.x),f2bf(f2.y),f2bf(f2.z),f2bf(f2.w),
                       f2bf(f3.x),f2bf(f3.y),f2bf(f3.z),f2bf(f3.w) };
    *(short8*)&xbrow[kt*64]   = *(short8*)&c[0];
    *(short8*)&xbrow[kt*64+8] = *(short8*)&c[8];
    *(short8*)&As[arow*64 + aslot0] = *(short8*)&c[0];
    *(short8*)&As[arow*64 + aslot1] = *(short8*)&c[8];
    if (kt < 15){
      f0 = *(const float4*)&xrow[(kt+1)*64 + 0];
      f1 = *(const float4*)&xrow[(kt+1)*64 + 4];
      f2 = *(const float4*)&xrow[(kt+1)*64 + 8];
      f3 = *(const float4*)&xrow[(kt+1)*64 +12];
    }
    __syncthreads();
    #pragma unroll
    for (int kk=0;kk<2;++kk){
      int row = w*16 + (lane&15);
      int g = kk*4 + (lane>>4);
      bf16x8 af = *(const bf16x8*)&As[row*64 + ((g^(row&7))<<3)];
      bf16x8 bfr = *(const bf16x8*)&wgt_t[(lane&15)*1040 + kt*64 + kk*32 + (lane>>4)*8];
      acc = MFMA16(af, bfr, acc);
    }
    __syncthreads();
  }
  #pragma unroll
  for (int r=0;r<4;++r){
    int grow = r0 + w*16 + (lane>>4)*4 + r;
    int bb = grow>>13, t = grow&(T_SEQ-1);
    float z = acc[r];
    float ls = fminf(z,0.f) - log1pf(__expf(-fabsf(z)));
    gtb[((size_t)(bb*NH + (lane&15)))*T_SEQ + t] = ls*(1.f/16.f);
  }
}

// ---------------- MFMA GEMM (R2-proven, 910 TF): C[M,N] = A[M,K] * Bt[N,K]^T ----------------
template<int OUT_BF16>
__global__ __launch_bounds__(256,2) void gemm_bt(const ushort_t* __restrict__ A,
    const ushort_t* __restrict__ Bt, void* __restrict__ Cv, int M, int N, int K,
    float* __restrict__ ssqp, int yoff){
  __shared__ __align__(16) ushort_t As[128*64];
  __shared__ __align__(16) ushort_t Bs[128*64];
  int tid = threadIdx.x;
  int lane = tid & 63, wid = tid >> 6;
  int wr = wid >> 1, wc = wid & 1;
  int m0 = blockIdx.x * 128, n0 = blockIdx.y * 128;
  f32x4 acc[4][4] = {};
  int srow = tid >> 3;
  int sg = tid & 7;
  const int nkt = K >> 6;
  for (int kt = 0; kt < nkt; ++kt){
    short8 ra[4], rb[4];
    #pragma unroll
    for (int s = 0; s < 4; ++s){
      int row = s*32 + srow;
      int gl = sg ^ (row & 7);
      ra[s] = *(const short8*)&A[(size_t)(m0 + row)*K + kt*64 + gl*8];
      rb[s] = *(const short8*)&Bt[(size_t)(n0 + row)*K + kt*64 + gl*8];
    }
    __syncthreads();
    #pragma unroll
    for (int s = 0; s < 4; ++s){
      int row = s*32 + srow;
      *(short8*)&As[row*64 + sg*8] = ra[s];
      *(short8*)&Bs[row*64 + sg*8] = rb[s];
    }
    __syncthreads();
    #pragma unroll
    for (int kk = 0; kk < 2; ++kk){
      bf16x8 af[4], bfv[4];
      #pragma unroll
      for (int m = 0; m < 4; ++m){
        int row = wr*64 + m*16 + (lane & 15);
        int g = kk*4 + (lane >> 4);
        af[m] = *(const bf16x8*)&As[row*64 + ((g ^ (row & 7))<<3)];
      }
      #pragma unroll
      for (int n = 0; n < 4; ++n){
        int row = wc*64 + n*16 + (lane & 15);
        int g = kk*4 + (lane >> 4);
        bfv[n] = *(const bf16x8*)&Bs[row*64 + ((g ^ (row & 7))<<3)];
      }
      #pragma unroll
      for (int m = 0; m < 4; ++m)
        #pragma unroll
        for (int n = 0; n < 4; ++n)
          acc[m][n] = MFMA16(af[m], bfv[n], acc[m][n]);
    }
  }
  #pragma unroll
  for (int m = 0; m < 4; ++m){
    int row = m0 + wr*64 + m*16 + (lane>>4)*4;
    #pragma unroll
    for (int n = 0; n < 4; ++n){
      int col = n0 + wc*64 + n*16 + (lane & 15);
      #pragma unroll
      for (int r = 0; r < 4; ++r){
        float v = acc[m][n][r];
        if (OUT_BF16) ((ushort_t*)Cv)[(size_t)(row+r)*N + col] = f2bf(v);
        else          ((float*)Cv)[(size_t)(row+r)*N + col] = v;
      }
    }
  }
  if (OUT_BF16 && (yoff + (int)blockIdx.y) < 24){
    int slot = (yoff + blockIdx.y)*2 + wc;
    #pragma unroll
    for (int m = 0; m < 4; ++m){
      #pragma unroll
      for (int r = 0; r < 4; ++r){
        float s = 0.f;
        #pragma unroll
        for (int n = 0; n < 4; ++n){ float xx = acc[m][n][r]; s += xx*xx; }
        s += __shfl_xor(s,1); s += __shfl_xor(s,2);
        s += __shfl_xor(s,4); s += __shfl_xor(s,8);
        if ((lane & 15) == 0){
          int row = m0 + wr*64 + m*16 + (lane>>4)*4 + r;
          ssqp[(size_t)slot*ROWS + row] = s;
        }
      }
    }
  }
}

// ---------------- combine ssq partials -> inverse rms per (mat,row) ----------------
__global__ __launch_bounds__(256) void rms_combine(const float* __restrict__ ssqp,
                                                   float* __restrict__ rmsb){
  int idx = blockIdx.x*256 + threadIdx.x;    // 3*16384
  int mat = idx >> 14, row = idx & (ROWS-1);
  float s = 0.f;
  #pragma unroll
  for (int k=0;k<16;++k) s += ssqp[(size_t)(mat*16+k)*ROWS + row];
  rmsb[idx] = rsqrtf(s*(1.f/1024.f)+1e-6f);
}

// ---------------- attention phase 1 (MFMA): kv = (k*rms_k*dec)^T (v*rms_v), kv bf16 [e][d] ----------------
__global__ __launch_bounds__(512,2) void attn_p1(const ushort_t* __restrict__ qkvg,
    const float* __restrict__ gtb, const float* __restrict__ rmsb,
    float* __restrict__ Bb, ushort_t* __restrict__ kvb){
  __shared__ __align__(16) ushort_t sh2[32768];   // kdt [64][256] | vt [64][256], swizzled
  __shared__ float bcf[256];
  __shared__ float tmp4[4];
  ushort_t* kdt = sh2;
  ushort_t* vt  = sh2 + 16384;
  int bid = blockIdx.x; int n = bid&31; int bh = bid>>5; int b = bh>>4; int h = bh&15;
  int t0 = n*CHK; int tid = threadIdx.x; int lane = tid&63; int w = tid>>6;
  float vscan = 0.f;
  if (tid < 256){
    vscan = gtb[(size_t)bh*T_SEQ + t0 + tid];
    #pragma unroll
    for (int off=1; off<64; off<<=1){ float u = __shfl_up(vscan, off); if (lane>=off) vscan += u; }
    if (lane==63) tmp4[w] = vscan;
  }
  __syncthreads();
  float Bn = tmp4[0]+tmp4[1]+tmp4[2]+tmp4[3];
  if (tid < 256){
    float pre=0;
    #pragma unroll
    for (int i=0;i<4;++i) if (i<w) pre += tmp4[i];
    bcf[tid] = vscan + pre;
  }
  if (tid==0) Bb[bid] = Bn;
  __syncthreads();
  {
    int j = tid>>1, dh = tid&1;
    int grow = b*T_SEQ + t0 + j;
    size_t rowb = (size_t)grow*4096;
    float fk = rmsb[ROWS + grow] * __expf(Bn - bcf[j]);
    float fv = rmsb[2*ROWS + grow];
    #pragma unroll
    for (int q8=0; q8<4; ++q8){
      short8 k8 = *(const short8*)&qkvg[rowb + 1024 + h*HD + dh*32 + q8*8];
      short8 v8 = *(const short8*)&qkvg[rowb + 2048 + h*HD + dh*32 + q8*8];
      #pragma unroll
      for (int kk=0; kk<8; ++kk){
        int d = dh*32 + q8*8 + kk;
        kdt[(d<<8) + (((j>>3)^(d&7))<<3) + (j&7)] = f2bf(bf2f((ushort_t)k8[kk])*fk);
        vt [(d<<8) + (((j>>3)^(d&7))<<3) + (j&7)] = f2bf(bf2f((ushort_t)v8[kk])*fv);
      }
    }
  }
  __syncthreads();
  if (w < 4){
    f32x4 acc[4] = {};
    #pragma unroll
    for (int s=0; s<8; ++s){
      int d = w*16 + (lane&15);
      int jj = s*32 + (lane>>4)*8;
      bf16x8 ka = *(const bf16x8*)&kdt[(d<<8) + (((jj>>3)^(d&7))<<3)];
      #pragma unroll
      for (int et=0; et<4; ++et){
        int e = et*16 + (lane&15);
        bf16x8 vf = *(const bf16x8*)&vt[(e<<8) + (((jj>>3)^(e&7))<<3)];
        acc[et] = MFMA16(ka, vf, acc[et]);
      }
    }
    ushort_t* kvp = &kvb[(size_t)bid*4096];
    #pragma unroll
    for (int et=0; et<4; ++et)
      #pragma unroll
      for (int r=0; r<4; ++r)
        kvp[(et*16 + (lane&15))*64 + w*16 + (lane>>4)*4 + r] = f2bf(acc[et][r]);
  }
}

// ---------------- state scan: one thread per (bh, e*64+d), coalesced, bf16 kv ----------------
__global__ __launch_bounds__(256) void scan_ker(const ushort_t* __restrict__ kvb,
    const float* __restrict__ Bb, ushort_t* __restrict__ Sb){
  int gidx = blockIdx.x*256 + threadIdx.x;
  int bh = gidx >> 12; int f = gidx & 4095;
  float S = 0.f;
  const ushort_t* kp = &kvb[(size_t)bh*NCHK*4096 + f];
  ushort_t* sp = &Sb[(size_t)bh*NCHK*4096 + f];
  for (int n=0;n<NCHK;++n){
    sp[(size_t)n*4096] = f2bf(S);
    S = __expf(Bb[bh*NCHK+n])*S + bf2f(kp[(size_t)n*4096]);
  }
}

// ---------------- attention phase 3: swapped QK^T + in-register P (no LDS round-trip) ----------------
__global__ __launch_bounds__(512,2) void attn_p3(const ushort_t* __restrict__ qkvg,
    const float* __restrict__ gtb, const float* __restrict__ rmsb,
    const ushort_t* __restrict__ Sb, ushort_t* __restrict__ oact){
  __shared__ __align__(16) ushort_t sh[(32768+16384+1024+32+2048)/2];
  ushort_t* vt = sh;                         // [e=64][j=256] swizzled
  ushort_t* ps = sh + 16384;                 // per-wave [32][32] swizzled (epilogue only)
  float* bcs = (float*)(sh + 24576);
  float* tmp = (float*)(sh + 25088);
  float* rqs = (float*)(sh + 25104);
  float* rks = (float*)(sh + 25616);
  int bid = blockIdx.x; int n = bid&31; int bh = bid>>5; int b = bh>>4; int h = bh&15;
  int t0 = n*CHK; int tid = threadIdx.x; int lane = tid&63; int w = tid>>6;
  int wrow = w*32;
  size_t chunkbase = (size_t)b*T_SEQ + t0;
  int qcol = lane & 15, hi = lane >> 4;
  bf16x8 qf[2][2];
  #pragma unroll
  for (int rt=0; rt<2; ++rt)
    #pragma unroll
    for (int s=0; s<2; ++s)
      qf[rt][s] = *(const bf16x8*)&qkvg[(chunkbase + wrow + rt*16 + qcol)*4096
                                        + h*HD + s*32 + hi*8];
  float vscan = 0.f;
  if (tid < 256){
    vscan = gtb[(size_t)bh*T_SEQ + t0 + tid];
    #pragma unroll
    for (int off=1; off<64; off<<=1){ float u = __shfl_up(vscan, off); if (lane>=off) vscan += u; }
    if (lane==63) tmp[w] = vscan;
  }
  __syncthreads();
  if (tid < 256){
    float pre=0;
    #pragma unroll
    for (int i=0;i<4;++i) if (i<w) pre += tmp[i];
    bcs[tid] = vscan + pre;
    int grow = b*T_SEQ + t0 + tid;
    rqs[tid] = rmsb[grow];
    rks[tid] = rmsb[ROWS + grow];
  }
  {
    int j = tid>>1, ehalf = tid&1;
    int grow = b*T_SEQ + t0 + j;
    size_t rowb = (size_t)grow*4096;
    float fv = rmsb[2*ROWS + grow];
    #pragma unroll
    for (int q8=0; q8<4; ++q8){
      short8 v8 = *(const short8*)&qkvg[rowb + 2048 + h*HD + ehalf*32 + q8*8];
      #pragma unroll
      for (int kk=0; kk<8; ++kk){
        int e = ehalf*32 + q8*8 + kk;
        vt[(e<<8) + (((j>>3)^(e&7))<<3) + (j&7)] = f2bf(bf2f((ushort_t)v8[kk])*fv);
      }
    }
  }
  __syncthreads();
  f32x4 o_[2][4] = {};
  #pragma unroll
  for (int s=0; s<2; ++s)
    #pragma unroll
    for (int et=0; et<4; ++et){
      bf16x8 stf = *(const bf16x8*)&Sb[(size_t)bid*4096 + (et*16 + qcol)*64 + s*32 + hi*8];
      #pragma unroll
      for (int rt=0; rt<2; ++rt)
        o_[rt][et] = MFMA16(qf[rt][s], stf, o_[rt][et]);
    }
  #pragma unroll
  for (int rt=0; rt<2; ++rt)
    #pragma unroll
    for (int rr=0; rr<4; ++rr){
      int ri = wrow + rt*16 + hi*4 + rr;
      float fs = 0.125f*__expf(bcs[ri])*rqs[ri];
      #pragma unroll
      for (int et=0; et<4; ++et) o_[rt][et][rr] *= fs;
    }
  float rqv[2], bqv[2];
  #pragma unroll
  for (int rt=0; rt<2; ++rt){
    int qr = wrow + rt*16 + qcol;
    rqv[rt] = rqs[qr]; bqv[rt] = bcs[qr];
  }
  int s0 = qcol + 32*(hi&1), s1 = s0 + 16;
  bool ctp = (hi >> 1) != 0;
  for (int hb=0; hb<=w; ++hb){
    int jbase = hb*32;
    bool dia = (hb == w);
    bf16x8 kf[2][2];
    #pragma unroll
    for (int s=0; s<2; ++s)
      #pragma unroll
      for (int ct=0; ct<2; ++ct)
        kf[s][ct] = *(const bf16x8*)&qkvg[(chunkbase + jbase + ct*16 + qcol)*4096
                                          + 1024 + h*HD + s*32 + hi*8];
    f32x4 s2[2][2] = {};
    #pragma unroll
    for (int s=0; s<2; ++s)
      #pragma unroll
      for (int ct=0; ct<2; ++ct)
        #pragma unroll
        for (int rt=0; rt<2; ++rt)
          s2[rt][ct] = MFMA16(kf[s][ct], qf[rt][s], s2[rt][ct]);
    bf16x8 vf[4];
    #pragma unroll
    for (int et=0; et<4; ++et){
      int e = et*16 + qcol;
      int jj = jbase + hi*8;
      vf[et] = *(const bf16x8*)&vt[(e<<8) + (((jj>>3) ^ (e&7))<<3)];
    }
    #pragma unroll
    for (int rt=0; rt<2; ++rt){
      int qr = wrow + rt*16 + qcol;
      unsigned wd[2][2];
      #pragma unroll
      for (int ct=0; ct<2; ++ct){
        float pv[4];
        #pragma unroll
        for (int rr=0; rr<4; ++rr){
          int kr = jbase + ct*16 + hi*4 + rr;
          float val = s2[rt][ct][rr] * 0.125f * rqv[rt] * rks[kr] * __expf(bqv[rt] - bcs[kr]);
          if (dia && kr > qr) val = 0.f;
          pv[rr] = val;
        }
        wd[ct][0] = ((unsigned)f2bf(pv[1])<<16) | f2bf(pv[0]);
        wd[ct][1] = ((unsigned)f2bf(pv[3])<<16) | f2bf(pv[2]);
      }
      unsigned a00 = (unsigned)__shfl((int)wd[0][0], s0);
      unsigned a10 = (unsigned)__shfl((int)wd[1][0], s0);
      unsigned a01 = (unsigned)__shfl((int)wd[0][1], s0);
      unsigned a11 = (unsigned)__shfl((int)wd[1][1], s0);
      unsigned b00 = (unsigned)__shfl((int)wd[0][0], s1);
      unsigned b10 = (unsigned)__shfl((int)wd[1][0], s1);
      unsigned b01 = (unsigned)__shfl((int)wd[0][1], s1);
      unsigned b11 = (unsigned)__shfl((int)wd[1][1], s1);
      union { unsigned u[4]; bf16x8 v; } pa;
      pa.u[0] = ctp ? a10 : a00;
      pa.u[1] = ctp ? a11 : a01;
      pa.u[2] = ctp ? b10 : b00;
      pa.u[3] = ctp ? b11 : b01;
      #pragma unroll
      for (int et=0; et<4; ++et)
        o_[rt][et] = MFMA16(pa.v, vf[et], o_[rt][et]);
    }
  }
  float rms8[2][4];
  #pragma unroll
  for (int rt=0; rt<2; ++rt)
    #pragma unroll
    for (int rr=0; rr<4; ++rr){
      float ssq = 0.f;
      #pragma unroll
      for (int et=0; et<4; ++et){ float xx = o_[rt][et][rr]; ssq += xx*xx; }
      ssq += __shfl_xor(ssq,1); ssq += __shfl_xor(ssq,2);
      ssq += __shfl_xor(ssq,4); ssq += __shfl_xor(ssq,8);
      rms8[rt][rr] = rsqrtf(ssq*(1.f/64.f)+1e-6f);
    }
  #pragma unroll
  for (int eh=0; eh<2; ++eh){
    #pragma unroll
    for (int rt=0; rt<2; ++rt)
      #pragma unroll
      for (int e2=0; e2<2; ++e2){
        int et = eh*2 + e2;
        #pragma unroll
        for (int rr=0; rr<4; ++rr){
          int pi = rt*16 + hi*4 + rr;
          int pj = e2*16 + qcol;
          ps[w*1024 + pi*32 + (((pj>>3) ^ ((pi>>2)&3))<<3) + (pj&7)] =
            f2bf(o_[rt][et][rr]*rms8[rt][rr]);
        }
      }
    int i2 = lane&31, e16 = (lane>>5)*16;
    int gr0 = e16>>3;
    int f = (i2>>2)&3;
    short8 ov0 = *(const short8*)&ps[w*1024 + i2*32 + ((gr0^f)<<3)];
    short8 ov1 = *(const short8*)&ps[w*1024 + i2*32 + (((gr0+1)^f)<<3)];
    size_t rowg = chunkbase + wrow + i2;
    short8 gv0 = *(const short8*)&qkvg[rowg*4096 + 3072 + h*HD + eh*32 + e16];
    short8 gv1 = *(const short8*)&qkvg[rowg*4096 + 3072 + h*HD + eh*32 + e16 + 8];
    ushort_t outv[16];
    #pragma unroll
    for (int k=0;k<8;++k){
      float gf = bf2f((ushort_t)gv0[k]);
      float sg = gf/(1.f+__expf(-gf));
      outv[k] = f2bf(bf2f((ushort_t)ov0[k])*sg);
    }
    #pragma unroll
    for (int k=0;k<8;++k){
      float gf = bf2f((ushort_t)gv1[k]);
      float sg = gf/(1.f+__expf(-gf));
      outv[8+k] = f2bf(bf2f((ushort_t)ov1[k])*sg);
    }
    ushort_t* op = &oact[rowg*DIM + h*HD + eh*32 + e16];
    *(short8*)&op[0] = *(short8*)&outv[0];
    *(short8*)&op[8] = *(short8*)&outv[8];
  }
}

// ---------------- launch ----------------
extern "C" void kernel_launch(void* const* d_in, const int* in_sizes, int n_in,
                              void* d_out, int out_size, void* d_ws, size_t ws_size,
                              hipStream_t stream){
  const float* x  = (const float*)d_in[0];
  const float* Wq = (const float*)d_in[1];
  const float* Wk = (const float*)d_in[2];
  const float* Wv = (const float*)d_in[3];
  const float* Wg = (const float*)d_in[4];
  const float* Wgt= (const float*)d_in[5];
  const float* Wo = (const float*)d_in[6];
  float* out = (float*)d_out;

  char* p = (char*)d_ws;
  ushort_t* xbf  = (ushort_t*)p; p += (size_t)ROWS*DIM*2;
  ushort_t* wcat = (ushort_t*)p; p += (size_t)4*DIM*DIM*2;
  ushort_t* wot  = (ushort_t*)p; p += (size_t)DIM*DIM*2;
  ushort_t* qkvg = (ushort_t*)p; p += (size_t)ROWS*4096*2;
  float* gtb = (float*)p; p += (size_t)32*T_SEQ*4;
  float* Bb  = (float*)p; p += 1024*4;
  ushort_t* kvb = (ushort_t*)p; p += (size_t)1024*4096*2;
  ushort_t* Sb = (ushort_t*)p; p += (size_t)1024*4096*2;
  ushort_t* oact = (ushort_t*)p; p += (size_t)ROWS*DIM*2;
  float* ssqp = (float*)p; p += (size_t)48*ROWS*4;
  float* rmsb = (float*)p; p += (size_t)3*ROWS*4;
  if ((size_t)(p - (char*)d_ws) > ws_size) return;

  cast_gt_ker<<<ROWS/64,256,0,stream>>>(x, Wgt, xbf, gtb);
  transpose_all<<<dim3(16,16,5),256,0,stream>>>(Wq, Wk, Wv, Wg, Wo, wcat, wot);
  gemm_bt<1><<<dim3(ROWS/128, 4096/128), 256, 0, stream>>>(xbf, wcat, qkvg, ROWS, 4096, DIM, ssqp, 0);
  rms_combine<<<(3*ROWS)/256,256,0,stream>>>(ssqp, rmsb);
  attn_p1<<<1024,512,0,stream>>>(qkvg, gtb, rmsb, Bb, kvb);
  scan_ker<<<512,256,0,stream>>>(kvb, Bb, Sb);
  attn_p3<<<1024,512,0,stream>>>(qkvg, gtb, rmsb, Sb, oact);
  gemm_bt<0><<<dim3(ROWS/128, 1024/128), 256, 0, stream>>>(oact, wot, out, ROWS, 1024, DIM, nullptr, 0);
}